// Round 5
// baseline (361.460 us; speedup 1.0000x reference)
//
#include <hip/hip_runtime.h>
#include <math.h>

typedef __attribute__((ext_vector_type(8))) _Float16 half8;
typedef __attribute__((ext_vector_type(4))) float float4_t;

#define NB 2048
#define LL 200
#define DD 128
#define AA 64
#define NEG_INF_F -4294967295.0f  // rounds to -2^32 in fp32, matches reference

#define WQ_STRIDE 136   // halves: 128 + 8 pad; 272 B row, 16B-aligned chunks

// ws layout (halves):
//   wbc16 [64][136] @ 0      : fp16 (W1b - W1c)^T, row a, padded
//   w1d16 [64][136] @ 8704   : fp16 W1d^T, row a, padded
//   W2T   [64][64]  @ 17408  : fp16 W2 transposed [c][a]
//   qa fp32 @ byte 43008     : [2048][64]  b1 + q@(W1a+W1c)
#define WS_WBC_H  0
#define WS_W1D_H  8704
#define WS_W2T_H  17408
#define WS_QA_OFF 43008

// ---------------- K1: weight transforms + qA (unchanged from R4) ----------------
__global__ __launch_bounds__(256)
void din_prep(const float* __restrict__ query,
              const float* __restrict__ W1,
              const float* __restrict__ b1,
              const float* __restrict__ W2,
              _Float16* __restrict__ ws16,
              float* __restrict__ qa)
{
    const int tid = threadIdx.x;
    const int blk = blockIdx.x;

    if (blk < 128) {
        __shared__ float sW1s[DD * AA];   // W1a + W1c
        __shared__ float sq[16 * DD];
        const int b0 = blk * 16;
        for (int i = tid; i < DD * AA; i += 256)
            sW1s[i] = W1[i] + W1[2 * DD * AA + i];
        for (int i = tid; i < 16 * DD; i += 256)
            sq[i] = query[(size_t)b0 * DD + i];
        __syncthreads();
        const int lane = tid & 63, bb = tid >> 6;
        for (int g = 0; g < 4; ++g) {
            const int bi = bb * 4 + g;
            float acc = b1[lane];
            #pragma unroll 8
            for (int d = 0; d < DD; ++d)
                acc += sq[bi * DD + d] * sW1s[d * AA + lane];
            qa[(size_t)(b0 + bi) * AA + lane] = acc;
        }
    } else if (blk == 128) {
        for (int i = tid; i < 64 * 17; i += 256) {
            const int a = i / 17, c = i - a * 17;
            half8 hb, hd;
            if (c == 16) {
                #pragma unroll
                for (int j = 0; j < 8; ++j) { hb[j] = (_Float16)0.f; hd[j] = (_Float16)0.f; }
            } else {
                const int d0 = c * 8;
                #pragma unroll
                for (int j = 0; j < 8; ++j) {
                    const int d = d0 + j;
                    hb[j] = (_Float16)(W1[(DD + d) * AA + a] - W1[(2 * DD + d) * AA + a]);
                    hd[j] = (_Float16)(W1[(3 * DD + d) * AA + a]);
                }
            }
            *(half8*)&ws16[WS_WBC_H + a * WQ_STRIDE + c * 8] = hb;
            *(half8*)&ws16[WS_W1D_H + a * WQ_STRIDE + c * 8] = hd;
        }
    } else {
        _Float16* w2t = ws16 + WS_W2T_H;
        const int c = tid >> 2, j0 = (tid & 3) * 16;
        for (int ch = 0; ch < 2; ++ch) {
            half8 v;
            #pragma unroll
            for (int j = 0; j < 8; ++j)
                v[j] = (_Float16)W2[(j0 + ch * 8 + j) * AA + c];
            *(half8*)&w2t[c * AA + j0 + ch * 8] = v;
        }
    }
}

// ---------------- K2: wave-independent flash-style main kernel ----------------
// One batch per block, 4 waves. Each wave: stage its own 16-row key tile (private
// LDS slot, XOR-swizzled), GEMM1 -> h1 -> GEMM2 -> scores, then ONLINE-softmax
// accumulation of O (per wave,quad running max m + rescale). No block barrier in
// the main loop. Final: global softmax from sS + combine O_wq with exp(m_wq - M).
__global__ __launch_bounds__(256, 3)
void din_main(const float* __restrict__ keys,
              const int*   __restrict__ keys_length,
              const float* __restrict__ a1p,
              const float* __restrict__ b2,
              const float* __restrict__ a2p,
              const float* __restrict__ W3,
              const _Float16* __restrict__ ws16,
              const float* __restrict__ qa,
              const float* __restrict__ query,
              float* __restrict__ out,
              float* __restrict__ att)
{
    __shared__ __align__(16) _Float16 sWq[AA * WQ_STRIDE];   // 17408 B
    __shared__ __align__(16) _Float16 sTile[4 * 16 * DD];    // 16384 B, per-wave 4 KB slots
    __shared__ __align__(16) _Float16 sH1[4 * 16 * 72];      //  9216 B (h1; aliased as O scratch)
    __shared__ float sQ[136];
    __shared__ float sS[224];
    __shared__ float sML[16];
    __shared__ float sRed[16];

    const int tid  = threadIdx.x;
    const int lane = tid & 63, wv = tid >> 6;
    const int col  = lane & 15, quad = lane >> 4;
    const int b    = blockIdx.x;
    const int len  = keys_length[b];
    const float pa1 = a1p[0], pa2 = a2p[0];

    if (tid < 136) sQ[tid] = (tid < 128) ? query[(size_t)b * DD + tid] : 0.f;
    for (int i = tid; i < 224; i += 256) sS[i] = NEG_INF_F;
    __syncthreads();

    // ---- build sWq[a][d] = (W1b-W1c) + q[d]*W1d  (coalesced fp16 reads, L2-hot) ----
    for (int ci = tid; ci < 64 * 17; ci += 256) {
        const int c = ci % 17;
        const int d0 = c * 8;                 // c==16 -> pad chunk, sQ[128..135]==0
        const half8 hb = *(const half8*)&ws16[WS_WBC_H + ci * 8];
        const half8 hd = *(const half8*)&ws16[WS_W1D_H + ci * 8];
        half8 r;
        #pragma unroll
        for (int j = 0; j < 8; ++j)
            r[j] = (_Float16)((float)hb[j] + sQ[d0 + j] * (float)hd[j]);
        *(half8*)&sWq[ci * 8] = r;
    }
    __syncthreads();

    // ---- per-lane constants ----
    const _Float16* w2t = ws16 + WS_W2T_H;
    half8 w2f[2][4];
    #pragma unroll
    for (int ks = 0; ks < 2; ++ks)
        #pragma unroll
        for (int n = 0; n < 4; ++n)
            w2f[ks][n] = *(const half8*)&w2t[(n * 16 + col) * AA + ks * 32 + quad * 8];
    float qareg[4], b2reg[4], w3reg[4];
    #pragma unroll
    for (int n = 0; n < 4; ++n) {
        qareg[n] = qa[(size_t)b * AA + n * 16 + col];
        b2reg[n] = b2[n * 16 + col];
        w3reg[n] = W3[n * 16 + col];
    }

    const int ntiles = (len + 15) >> 4;
    _Float16* const myTile = &sTile[wv * 16 * DD];
    _Float16* const myH    = &sH1[wv * 16 * 72];

    float m_run = -INFINITY;
    float O[8];
    #pragma unroll
    for (int j = 0; j < 8; ++j) O[j] = 0.f;

    for (int t = wv; t < ntiles; t += 4) {
        const int l0 = t * 16;

        // ---- stage my 16x128 tile -> fp16 swizzled LDS (wave-private, no barrier) ----
        #pragma unroll
        for (int it = 0; it < 4; ++it) {
            const int i = lane + 64 * it;
            const int row = i >> 4, c8 = i & 15;
            const int l = l0 + row;
            const int lr = (l < LL) ? l : (LL - 1);   // clamp; masked via e=0 later
            const float* kp = keys + ((size_t)b * LL + lr) * DD + c8 * 8;
            const float4 v0 = *(const float4*)kp;
            const float4 v1 = *(const float4*)(kp + 4);
            half8 h;
            h[0] = (_Float16)v0.x; h[1] = (_Float16)v0.y; h[2] = (_Float16)v0.z; h[3] = (_Float16)v0.w;
            h[4] = (_Float16)v1.x; h[5] = (_Float16)v1.y; h[6] = (_Float16)v1.z; h[7] = (_Float16)v1.w;
            *(half8*)&myTile[row * DD + ((c8 ^ (row & 7)) << 3)] = h;
        }

        // ---- GEMM1: C(16x64) = tile(16x128) @ Wq(128x64) ----
        float4_t C[4] = {{0,0,0,0},{0,0,0,0},{0,0,0,0},{0,0,0,0}};
        #pragma unroll
        for (int ks = 0; ks < 4; ++ks) {
            const half8 af = *(const half8*)&myTile[col * DD + (((ks * 4 + quad) ^ (col & 7)) << 3)];
            const int ko = ks * 32 + quad * 8;
            #pragma unroll
            for (int n = 0; n < 4; ++n) {
                const half8 bf = *(const half8*)&sWq[(n * 16 + col) * WQ_STRIDE + ko];
                C[n] = __builtin_amdgcn_mfma_f32_16x16x32_f16(af, bf, C[n], 0, 0, 0);
            }
        }
        // epilogue: +qA, PReLU(a1) -> myH [m][a]
        #pragma unroll
        for (int n = 0; n < 4; ++n)
            #pragma unroll
            for (int r = 0; r < 4; ++r) {
                float v = C[n][r] + qareg[n];
                v = v >= 0.f ? v : pa1 * v;
                myH[(quad * 4 + r) * 72 + n * 16 + col] = (_Float16)v;
            }
        // ---- GEMM2: D(16x64) = h1 @ W2, B from registers ----
        float4_t D[4] = {{0,0,0,0},{0,0,0,0},{0,0,0,0},{0,0,0,0}};
        #pragma unroll
        for (int ks = 0; ks < 2; ++ks) {
            const half8 af = *(const half8*)&myH[col * 72 + ks * 32 + quad * 8];
            #pragma unroll
            for (int n = 0; n < 4; ++n)
                D[n] = __builtin_amdgcn_mfma_f32_16x16x32_f16(af, w2f[ks][n], D[n], 0, 0, 0);
        }
        // layer3: +b2, PReLU(a2), dot W3; shfl-reduce over 16 col lanes (b3 shift-invariant)
        float pr[4] = {0.f, 0.f, 0.f, 0.f};
        #pragma unroll
        for (int n = 0; n < 4; ++n)
            #pragma unroll
            for (int r = 0; r < 4; ++r) {
                float v = D[n][r] + b2reg[n];
                v = v >= 0.f ? v : pa2 * v;
                pr[r] += v * w3reg[n];
            }
        float sv[4];
        #pragma unroll
        for (int r = 0; r < 4; ++r) {
            float pv = pr[r];
            pv += __shfl_xor(pv, 1);
            pv += __shfl_xor(pv, 2);
            pv += __shfl_xor(pv, 4);
            pv += __shfl_xor(pv, 8);
            const int l = l0 + quad * 4 + r;
            const bool valid = (l < len);
            sv[r] = valid ? pv : -INFINITY;
            if (col == 0 && valid) sS[l] = pv;
        }
        // ---- online-softmax O update (per wave,quad; rows quad*4+r of this tile) ----
        const float tmax = fmaxf(fmaxf(sv[0], sv[1]), fmaxf(sv[2], sv[3]));
        const float newm = fmaxf(m_run, tmax);
        if (newm != -INFINITY) {                    // whole quad-slice masked -> skip
            const float alpha = expf(m_run - newm); // m_run=-inf -> 0 (first contribution)
            #pragma unroll
            for (int j = 0; j < 8; ++j) O[j] *= alpha;
            #pragma unroll
            for (int r = 0; r < 4; ++r) {
                const float e = (sv[r] == -INFINITY) ? 0.f : expf(sv[r] - newm);
                const int rr = quad * 4 + r;
                const half8 kv = *(const half8*)&myTile[rr * DD + ((col ^ (rr & 7)) << 3)];
                #pragma unroll
                for (int j = 0; j < 8; ++j) O[j] += e * (float)kv[j];
            }
            m_run = newm;
        }
    }

    // ---- write per-(wave,quad) partials: O -> myH alias, m -> sML ----
    float* const myO = (float*)myH;   // 512 floats fit the 2304 B slot
    #pragma unroll
    for (int j = 0; j < 8; ++j) myO[quad * 128 + col * 8 + j] = O[j];
    if (col == 0) sML[wv * 4 + quad] = m_run;
    __syncthreads();

    // ---- global masked softmax over sS[0..199] ----
    float m = (tid < LL) ? sS[tid] : -INFINITY;
    #pragma unroll
    for (int o = 1; o < 64; o <<= 1) m = fmaxf(m, __shfl_xor(m, o));
    if (lane == 0) sRed[wv] = m;
    __syncthreads();
    const float M = fmaxf(fmaxf(sRed[0], sRed[1]), fmaxf(sRed[2], sRed[3]));
    float e = (tid < LL) ? expf(sS[tid] - M) : 0.f;
    float s = e;
    #pragma unroll
    for (int o = 1; o < 64; o <<= 1) s += __shfl_xor(s, o);
    if (lane == 0) sRed[8 + wv] = s;
    __syncthreads();
    const float S = sRed[8] + sRed[9] + sRed[10] + sRed[11];
    const float inv = 1.f / S;
    if (tid < LL) att[(size_t)b * LL + tid] = e * inv;

    // ---- combine: out[d] = inv * sum_wq exp(m_wq - M) * O_wq[d] ----
    if (tid < 16) sML[tid] = expf(sML[tid] - M);   // -inf -> 0 (empty slices)
    __syncthreads();

    if (len > 0) {
        if (tid < DD) {
            const float* fO = (const float*)sH1;
            float r = 0.f;
            #pragma unroll
            for (int w = 0; w < 4; ++w)
                #pragma unroll
                for (int q = 0; q < 4; ++q)
                    r += sML[w * 4 + q] * fO[w * 576 + q * 128 + tid];
            out[(size_t)b * DD + tid] = r * inv;
        }
    } else {
        // len==0: att is uniform 1/200 (softmax path above already wrote it);
        // out = mean over all 200 rows, read coalesced from global.
        const int d = tid & 127, ph = tid >> 7;
        float acc = 0.f;
        for (int l = ph; l < LL; l += 2)
            acc += keys[((size_t)b * LL + l) * DD + d];
        float* const sc = (float*)sTile;
        sc[tid] = acc;
        __syncthreads();
        if (tid < DD)
            out[(size_t)b * DD + tid] = (sc[tid] + sc[tid + 128]) * (1.f / 200.f);
    }
}

extern "C" void kernel_launch(void* const* d_in, const int* in_sizes, int n_in,
                              void* d_out, int out_size, void* d_ws, size_t ws_size,
                              hipStream_t stream) {
    (void)in_sizes; (void)n_in; (void)ws_size; (void)out_size;
    const float* query = (const float*)d_in[0];
    const float* keys  = (const float*)d_in[1];
    const int*   klen  = (const int*)d_in[2];
    const float* W1    = (const float*)d_in[3];
    const float* b1    = (const float*)d_in[4];
    const float* a1    = (const float*)d_in[5];
    const float* W2    = (const float*)d_in[6];
    const float* b2    = (const float*)d_in[7];
    const float* a2    = (const float*)d_in[8];
    const float* W3    = (const float*)d_in[9];
    // d_in[10] = b3: irrelevant to both outputs (softmax shift invariance)

    _Float16* ws16 = (_Float16*)d_ws;
    float*    qawk = (float*)((char*)d_ws + WS_QA_OFF);

    float* out = (float*)d_out;                  // (B, D) fp32
    float* att = out + (size_t)NB * DD;          // (B, L) fp32

    hipLaunchKernelGGL(din_prep, dim3(130), dim3(256), 0, stream,
                       query, W1, b1, W2, ws16, qawk);
    hipLaunchKernelGGL(din_main, dim3(NB), dim3(256), 0, stream,
                       keys, klen, a1, b2, a2, W3, ws16, qawk, query, out, att);
}

// Round 6
// 329.840 us; speedup vs baseline: 1.0959x; 1.0959x over previous
//
#include <hip/hip_runtime.h>
#include <math.h>

typedef __attribute__((ext_vector_type(8))) _Float16 half8;
typedef __attribute__((ext_vector_type(4))) float float4_t;

#define NB 2048
#define LL 200
#define DD 128
#define AA 64
#define NEG_INF_F -4294967295.0f  // rounds to -2^32 in fp32, matches reference

#define WQ_STRIDE 136   // halves: 128 + 8 pad; 272 B row, 16B-aligned chunks

// ws layout (halves):
//   wbc16 [64][136] @ 0      : fp16 (W1b - W1c)^T, row a, padded
//   w1d16 [64][136] @ 8704   : fp16 W1d^T, row a, padded
//   W2T   [64][64]  @ 17408  : fp16 W2 transposed [c][a]
//   qa fp32 @ byte 43008     : [2048][64]  b1 + q@(W1a+W1c)
#define WS_WBC_H  0
#define WS_W1D_H  8704
#define WS_W2T_H  17408
#define WS_QA_OFF 43008

// ---------------- K1: weight transforms + qA (wider: 4 batches/block) ----------------
__global__ __launch_bounds__(256)
void din_prep(const float* __restrict__ query,
              const float* __restrict__ W1,
              const float* __restrict__ b1,
              const float* __restrict__ W2,
              _Float16* __restrict__ ws16,
              float* __restrict__ qa)
{
    const int tid = threadIdx.x;
    const int blk = blockIdx.x;

    if (blk < 512) {
        __shared__ float sW1s[DD * AA];   // W1a + W1c
        __shared__ float sq[4 * DD];
        const int b0 = blk * 4;
        for (int i = tid; i < DD * AA; i += 256)
            sW1s[i] = W1[i] + W1[2 * DD * AA + i];
        for (int i = tid; i < 4 * DD; i += 256)
            sq[i] = query[(size_t)b0 * DD + i];
        __syncthreads();
        const int lane = tid & 63, bi = tid >> 6;   // one batch per wave
        float acc = b1[lane];
        #pragma unroll 8
        for (int d = 0; d < DD; ++d)
            acc += sq[bi * DD + d] * sW1s[d * AA + lane];
        qa[(size_t)(b0 + bi) * AA + lane] = acc;
    } else if (blk == 512) {
        // wbc16[a][d] = W1b - W1c ; w1d16[a][d] = W1d ; pad cols 128..135 = 0
        for (int i = tid; i < 64 * 17; i += 256) {
            const int a = i / 17, c = i - a * 17;
            half8 hb, hd;
            if (c == 16) {
                #pragma unroll
                for (int j = 0; j < 8; ++j) { hb[j] = (_Float16)0.f; hd[j] = (_Float16)0.f; }
            } else {
                const int d0 = c * 8;
                #pragma unroll
                for (int j = 0; j < 8; ++j) {
                    const int d = d0 + j;
                    hb[j] = (_Float16)(W1[(DD + d) * AA + a] - W1[(2 * DD + d) * AA + a]);
                    hd[j] = (_Float16)(W1[(3 * DD + d) * AA + a]);
                }
            }
            *(half8*)&ws16[WS_WBC_H + a * WQ_STRIDE + c * 8] = hb;
            *(half8*)&ws16[WS_W1D_H + a * WQ_STRIDE + c * 8] = hd;
        }
    } else {
        // W2T[c][a] dense 64x64 fp16
        _Float16* w2t = ws16 + WS_W2T_H;
        const int c = tid >> 2, j0 = (tid & 3) * 16;
        for (int ch = 0; ch < 2; ++ch) {
            half8 v;
            #pragma unroll
            for (int j = 0; j < 8; ++j)
                v[j] = (_Float16)W2[(j0 + ch * 8 + j) * AA + c];
            *(half8*)&w2t[c * AA + j0 + ch * 8] = v;
        }
    }
}

// ---------------- K2: R4 structure + register Wq + pipelined staging ----------------
// One batch per block, 4 waves, keys staged ONCE (coalesced, fp16, XOR-swizzled).
// GEMM1 B-frags (Wq) and GEMM2 B-frags (W2) live in registers; only A-frags hit LDS.
__global__ __launch_bounds__(256, 2)
void din_main(const float* __restrict__ keys,
              const int*   __restrict__ keys_length,
              const float* __restrict__ a1p,
              const float* __restrict__ b2,
              const float* __restrict__ a2p,
              const float* __restrict__ W3,
              const _Float16* __restrict__ ws16,
              const float* __restrict__ qa,
              const float* __restrict__ query,
              float* __restrict__ out,
              float* __restrict__ att)
{
    __shared__ __align__(16) _Float16 sKeys[LL * DD];     // 51200 B
    __shared__ __align__(16) _Float16 sH1[4 * 16 * 72];   //  9216 B (h1; float scratch later)
    __shared__ float sS[224];
    __shared__ float sRed[16];

    const int tid  = threadIdx.x;
    const int lane = tid & 63, wv = tid >> 6;
    const int col  = lane & 15, quad = lane >> 4;
    const int b    = blockIdx.x;
    const int len  = keys_length[b];
    const float pa1 = a1p[0], pa2 = a2p[0];
    const int Lcap = (len == 0) ? LL : len;   // len==0 -> uniform att over all 200 rows

    for (int i = tid; i < 224; i += 256) sS[i] = NEG_INF_F;

    // ---- Wq B-fragments in registers: wq[a][d] = (W1b-W1c) + q[d]*W1d (L2-hot) ----
    half8 wqf[4][4];
    #pragma unroll
    for (int ks = 0; ks < 4; ++ks) {
        const int d0 = ks * 32 + quad * 8;
        const float4 q0 = *(const float4*)(query + (size_t)b * DD + d0);
        const float4 q1 = *(const float4*)(query + (size_t)b * DD + d0 + 4);
        float qv[8];
        qv[0] = q0.x; qv[1] = q0.y; qv[2] = q0.z; qv[3] = q0.w;
        qv[4] = q1.x; qv[5] = q1.y; qv[6] = q1.z; qv[7] = q1.w;
        #pragma unroll
        for (int n = 0; n < 4; ++n) {
            const int a = n * 16 + col;
            const half8 hb = *(const half8*)&ws16[WS_WBC_H + a * WQ_STRIDE + d0];
            const half8 hd = *(const half8*)&ws16[WS_W1D_H + a * WQ_STRIDE + d0];
            half8 r;
            #pragma unroll
            for (int j = 0; j < 8; ++j)
                r[j] = (_Float16)((float)hb[j] + qv[j] * (float)hd[j]);
            wqf[ks][n] = r;
        }
    }
    // W2 B-frags + per-lane constants
    const _Float16* w2t = ws16 + WS_W2T_H;
    half8 w2f[2][4];
    #pragma unroll
    for (int ks = 0; ks < 2; ++ks)
        #pragma unroll
        for (int n = 0; n < 4; ++n)
            w2f[ks][n] = *(const half8*)&w2t[(n * 16 + col) * AA + ks * 32 + quad * 8];
    float qareg[4], b2reg[4], w3reg[4];
    #pragma unroll
    for (int n = 0; n < 4; ++n) {
        qareg[n] = qa[(size_t)b * AA + n * 16 + col];
        b2reg[n] = b2[n * 16 + col];
        w3reg[n] = W3[n * 16 + col];
    }

    // ---- stage keys rows [0,Lcap) -> fp16 swizzled LDS; 2-phase pipelined ----
    const int NI = Lcap * 16;   // number of 8-half chunks
    {
        float4 va[7], vb[7];
        #pragma unroll
        for (int it = 0; it < 7; ++it) {
            const int i = tid + it * 256;
            const int ii = (i < NI) ? i : (NI - 1);      // clamp: dup loads stay in-range
            const float* kp = keys + ((size_t)b * LL + (ii >> 4)) * DD + (ii & 15) * 8;
            va[it] = *(const float4*)kp;
            vb[it] = *(const float4*)(kp + 4);
        }
        #pragma unroll
        for (int it = 0; it < 7; ++it) {
            const int i = tid + it * 256;
            if (i < NI) {
                const int l = i >> 4, c8 = i & 15;
                half8 h;
                h[0] = (_Float16)va[it].x; h[1] = (_Float16)va[it].y;
                h[2] = (_Float16)va[it].z; h[3] = (_Float16)va[it].w;
                h[4] = (_Float16)vb[it].x; h[5] = (_Float16)vb[it].y;
                h[6] = (_Float16)vb[it].z; h[7] = (_Float16)vb[it].w;
                *(half8*)&sKeys[l * DD + ((c8 ^ (l & 7)) << 3)] = h;
            }
        }
        float4 vc[6], vd[6];
        #pragma unroll
        for (int it = 0; it < 6; ++it) {
            const int i = tid + (7 + it) * 256;
            const int ii = (i < NI) ? i : (NI - 1);
            const float* kp = keys + ((size_t)b * LL + (ii >> 4)) * DD + (ii & 15) * 8;
            vc[it] = *(const float4*)kp;
            vd[it] = *(const float4*)(kp + 4);
        }
        #pragma unroll
        for (int it = 0; it < 6; ++it) {
            const int i = tid + (7 + it) * 256;
            if (i < NI) {
                const int l = i >> 4, c8 = i & 15;
                half8 h;
                h[0] = (_Float16)vc[it].x; h[1] = (_Float16)vc[it].y;
                h[2] = (_Float16)vc[it].z; h[3] = (_Float16)vc[it].w;
                h[4] = (_Float16)vd[it].x; h[5] = (_Float16)vd[it].y;
                h[6] = (_Float16)vd[it].z; h[7] = (_Float16)vd[it].w;
                *(half8*)&sKeys[l * DD + ((c8 ^ (l & 7)) << 3)] = h;
            }
        }
    }
    __syncthreads();

    // ---- main loop: each wave owns tiles t = wv, wv+4, ... ----
    const int ntiles = (len + 15) >> 4;
    _Float16* const myH = &sH1[wv * 16 * 72];

    for (int t = wv; t < ntiles; t += 4) {
        const int l0 = t * 16;
        const int lr = (l0 + col < LL) ? (l0 + col) : (LL - 1);  // clamp; rows>=len masked below

        // GEMM1: C(16x64) = keys(16x128) @ Wq(128x64); A from LDS, B from regs
        float4_t C[4] = {{0,0,0,0},{0,0,0,0},{0,0,0,0},{0,0,0,0}};
        #pragma unroll
        for (int ks = 0; ks < 4; ++ks) {
            const half8 af = *(const half8*)&sKeys[lr * DD + (((ks * 4 + quad) ^ (lr & 7)) << 3)];
            #pragma unroll
            for (int n = 0; n < 4; ++n)
                C[n] = __builtin_amdgcn_mfma_f32_16x16x32_f16(af, wqf[ks][n], C[n], 0, 0, 0);
        }
        // epilogue: +qA, PReLU(a1) -> myH [m][a]
        #pragma unroll
        for (int n = 0; n < 4; ++n)
            #pragma unroll
            for (int r = 0; r < 4; ++r) {
                float v = C[n][r] + qareg[n];
                v = v >= 0.f ? v : pa1 * v;
                myH[(quad * 4 + r) * 72 + n * 16 + col] = (_Float16)v;
            }
        // GEMM2: D(16x64) = h1 @ W2; B from regs
        float4_t D[4] = {{0,0,0,0},{0,0,0,0},{0,0,0,0},{0,0,0,0}};
        #pragma unroll
        for (int ks = 0; ks < 2; ++ks) {
            const half8 af = *(const half8*)&myH[col * 72 + ks * 32 + quad * 8];
            #pragma unroll
            for (int n = 0; n < 4; ++n)
                D[n] = __builtin_amdgcn_mfma_f32_16x16x32_f16(af, w2f[ks][n], D[n], 0, 0, 0);
        }
        // layer3: +b2, PReLU(a2), dot W3; shfl-reduce 16 col lanes (b3 shift-invariant)
        float pr[4] = {0.f, 0.f, 0.f, 0.f};
        #pragma unroll
        for (int n = 0; n < 4; ++n)
            #pragma unroll
            for (int r = 0; r < 4; ++r) {
                float v = D[n][r] + b2reg[n];
                v = v >= 0.f ? v : pa2 * v;
                pr[r] += v * w3reg[n];
            }
        #pragma unroll
        for (int r = 0; r < 4; ++r) {
            float pv = pr[r];
            pv += __shfl_xor(pv, 1);
            pv += __shfl_xor(pv, 2);
            pv += __shfl_xor(pv, 4);
            pv += __shfl_xor(pv, 8);
            const int l = l0 + quad * 4 + r;
            if (col == 0 && l < len) sS[l] = pv;
        }
    }

    __syncthreads();
    // ---- masked softmax over sS[0..199] (len==0 -> all NEG_INF -> uniform) ----
    float m = (tid < LL) ? sS[tid] : -INFINITY;
    #pragma unroll
    for (int o = 1; o < 64; o <<= 1) m = fmaxf(m, __shfl_xor(m, o));
    if (lane == 0) sRed[wv] = m;
    __syncthreads();
    const float M = fmaxf(fmaxf(sRed[0], sRed[1]), fmaxf(sRed[2], sRed[3]));
    float e = (tid < LL) ? expf(sS[tid] - M) : 0.f;
    float s = e;
    #pragma unroll
    for (int o = 1; o < 64; o <<= 1) s += __shfl_xor(s, o);
    if (lane == 0) sRed[8 + wv] = s;
    __syncthreads();
    const float S = sRed[8] + sRed[9] + sRed[10] + sRed[11];
    const float inv = 1.f / S;
    if (tid < LL) {
        const float v = e * inv;
        sS[tid] = v;
        att[(size_t)b * LL + tid] = v;
    }
    __syncthreads();

    // ---- out[b][:] = sum_l att[l]*keys[l][:]  from sKeys fp16 ----
    {
        const int c8 = tid & 15, ph = tid >> 4;
        float acc[8];
        #pragma unroll
        for (int j = 0; j < 8; ++j) acc[j] = 0.f;
        for (int l = ph; l < Lcap; l += 16) {
            const float w = sS[l];
            const half8 kv = *(const half8*)&sKeys[l * DD + ((c8 ^ (l & 7)) << 3)];
            #pragma unroll
            for (int j = 0; j < 8; ++j) acc[j] += w * (float)kv[j];
        }
        float* const scratch = (float*)sH1;   // h1 dead
        #pragma unroll
        for (int j = 0; j < 8; ++j) scratch[tid * 8 + j] = acc[j];
        __syncthreads();
        if (tid < DD) {
            const int c8o = tid >> 3, j = tid & 7;
            float r = 0.f;
            #pragma unroll
            for (int p = 0; p < 16; ++p) r += scratch[(p * 16 + c8o) * 8 + j];
            out[(size_t)b * DD + tid] = r;
        }
    }
}

extern "C" void kernel_launch(void* const* d_in, const int* in_sizes, int n_in,
                              void* d_out, int out_size, void* d_ws, size_t ws_size,
                              hipStream_t stream) {
    (void)in_sizes; (void)n_in; (void)ws_size; (void)out_size;
    const float* query = (const float*)d_in[0];
    const float* keys  = (const float*)d_in[1];
    const int*   klen  = (const int*)d_in[2];
    const float* W1    = (const float*)d_in[3];
    const float* b1    = (const float*)d_in[4];
    const float* a1    = (const float*)d_in[5];
    const float* W2    = (const float*)d_in[6];
    const float* b2    = (const float*)d_in[7];
    const float* a2    = (const float*)d_in[8];
    const float* W3    = (const float*)d_in[9];
    // d_in[10] = b3: irrelevant to both outputs (softmax shift invariance)

    _Float16* ws16 = (_Float16*)d_ws;
    float*    qawk = (float*)((char*)d_ws + WS_QA_OFF);

    float* out = (float*)d_out;                  // (B, D) fp32
    float* att = out + (size_t)NB * DD;          // (B, L) fp32

    hipLaunchKernelGGL(din_prep, dim3(514), dim3(256), 0, stream,
                       query, W1, b1, W2, ws16, qawk);
    hipLaunchKernelGGL(din_main, dim3(NB), dim3(256), 0, stream,
                       keys, klen, a1, b2, a2, W3, ws16, qawk, query, out, att);
}